// Round 10
// baseline (253.296 us; speedup 1.0000x reference)
//
#include <hip/hip_runtime.h>
#include <hip/hip_bf16.h>
#include <hip/hip_fp16.h>

// ---------------------------------------------------------------------------
// 2-layer GAT, N=50000, E=1.6M (+N self loops).
// CSR build (hist / bucket-scan / counting-sort scatter / fused per-bucket
// build) -> GEMM1 [fp16 MFMA, fused alpha] -> agg1(fp16 out)
//  -> GEMM2 [fp16 MFMA, fused alpha] -> agg2 -> d_out.
// Softmax computed without max-shift (shift-invariant; |e| ~ 1.5).
// R2-R9: see journal. R10:
//  - agg kernels: 16B/lane gathers (8 ch/lane, 16 lanes/row) -> 4 edges
//    concurrent per wave in agg1, 8 in agg2; ~5.5 wave-instr/edge vs ~10;
//    VMEM instruction count /4. Cross-group reduce via shfl_xor(16,32).
//  - CSR: deg+scan_down+csr_scatter fused into csr_build_kernel (one pass
//    structure: LDS hist -> LDS scan -> LDS image), -2 launches.
// ---------------------------------------------------------------------------

#define LRELU_SLOPE 0.2f
#define NBMAX 200        // max dst buckets (N <= 51200)
#define NBLK  512        // blocks in hist/scatter passes
#define BCAP  16384      // per-bucket record capacity (mean ~8163)
#define CAPIMG 16384     // csr_build LDS image entries

typedef _Float16 f16x8 __attribute__((ext_vector_type(8)));
typedef float f32x4 __attribute__((ext_vector_type(4)));

// ---------------- CSR build ----------------

__global__ __launch_bounds__(256) void hist_kernel(const int* __restrict__ ei_dst,
                                                   int* __restrict__ hist, int E, int chunk) {
    __shared__ int h[NBMAX];
    int t = threadIdx.x;
    for (int i = t; i < NBMAX; i += 256) h[i] = 0;
    __syncthreads();
    int begin = blockIdx.x * chunk;
    int endE = min(E, begin + chunk);
    for (int e = begin + t; e < endE; e += 256) atomicAdd(&h[ei_dst[e] >> 8], 1);
    __syncthreads();
    for (int i = t; i < NBMAX; i += 256) hist[i * NBLK + blockIdx.x] = h[i];
}

__global__ __launch_bounds__(512) void bucket_scan_kernel(int* __restrict__ hist,
                                                          int* __restrict__ gfill) {
    __shared__ int buf[2][NBLK];
    int b = blockIdx.x, t = threadIdx.x;
    buf[0][t] = hist[b * NBLK + t];
    __syncthreads();
    int pi = 0;
#pragma unroll
    for (int off = 1; off < NBLK; off <<= 1) {
        int v = buf[pi][t];
        if (t >= off) v += buf[pi][t - off];
        buf[pi ^ 1][t] = v;
        __syncthreads();
        pi ^= 1;
    }
    hist[b * NBLK + t] = (t == 0) ? 0 : buf[pi][t - 1];
    if (t == 0) gfill[b] = buf[pi][NBLK - 1];
}

__global__ __launch_bounds__(256) void scatter2_kernel(const int* __restrict__ ei_src,
                                                       const int* __restrict__ ei_dst,
                                                       const int* __restrict__ hist,
                                                       unsigned int* __restrict__ records,
                                                       int E, int chunk) {
    __shared__ int base[NBMAX];
    __shared__ int lcnt[NBMAX];
    int t = threadIdx.x;
    for (int i = t; i < NBMAX; i += 256) {
        base[i] = hist[i * NBLK + blockIdx.x];
        lcnt[i] = 0;
    }
    __syncthreads();
    int begin = blockIdx.x * chunk;
    int endE = min(E, begin + chunk);
    for (int e = begin + t; e < endE; e += 256) {
        int s = ei_src[e], d = ei_dst[e];
        int bkt = d >> 8;
        unsigned int rec = (unsigned int)d | ((unsigned int)s << 16);
        int r = atomicAdd(&lcnt[bkt], 1);
        records[(size_t)bkt * BCAP + base[bkt] + r] = rec;
    }
}

// exclusive scan of per-bucket totals (records + valid self loops); row_ptr[n]
__global__ __launch_bounds__(256) void scan_blocksums_kernel(const int* __restrict__ gfill,
                                                             int* __restrict__ bsums,
                                                             int* __restrict__ row_ptr,
                                                             int nblocks, int n, int total) {
    __shared__ int buf[2][256];
    int t = threadIdx.x;
    int v0 = 0;
    if (t < nblocks) v0 = gfill[t] + min(256, n - (t << 8));
    buf[0][t] = v0;
    __syncthreads();
    int pi = 0;
#pragma unroll
    for (int off = 1; off < 256; off <<= 1) {
        int v = buf[pi][t];
        if (t >= off) v += buf[pi][t - off];
        buf[pi ^ 1][t] = v;
        __syncthreads();
        pi ^= 1;
    }
    if (t < nblocks) bsums[t] = (t == 0) ? 0 : buf[pi][t - 1];
    if (t == 0) row_ptr[n] = total;
}

// fused per-bucket: LDS hist -> LDS scan -> row_ptr slice -> LDS image -> col.
__global__ __launch_bounds__(256) void csr_build_kernel(const unsigned int* __restrict__ records,
                                                        const int* __restrict__ gfill,
                                                        const int* __restrict__ bsums,
                                                        int* __restrict__ row_ptr,
                                                        unsigned short* __restrict__ col,
                                                        int N) {
    __shared__ int cnt[256];
    __shared__ int buf[2][256];
    __shared__ unsigned short img[CAPIMG];
    __shared__ int lfill[256];
    int t = threadIdx.x, b = blockIdx.x;
    int gi = (b << 8) + t;
    bool valid = gi < N;
    cnt[t] = valid ? 1 : 0;   // self loop
    __syncthreads();
    int c = gfill[b];
    const unsigned int* r = records + (size_t)b * BCAP;
    for (int i = t; i < c; i += 256) atomicAdd(&cnt[r[i] & 255], 1);
    __syncthreads();
    int d = cnt[t];
    buf[0][t] = d;
    __syncthreads();
    int pi = 0;
#pragma unroll
    for (int off = 1; off < 256; off <<= 1) {
        int v = buf[pi][t];
        if (t >= off) v += buf[pi][t - off];
        buf[pi ^ 1][t] = v;
        __syncthreads();
        pi ^= 1;
    }
    int rbase = bsums[b];
    int nvalid = min(256, N - (b << 8));
    int size = c + max(nvalid, 0);
    bool lds = (size <= CAPIMG);
    if (valid) {
        int local = buf[pi][t] - d;  // exclusive prefix within bucket
        row_ptr[gi] = rbase + local;
        lfill[t] = local + 1;        // slot 0 = self loop
        if (lds) img[local] = (unsigned short)gi;
        else col[rbase + local] = (unsigned short)gi;
    }
    __syncthreads();
    for (int i = t; i < c; i += 256) {
        unsigned int rec = r[i];
        int d8 = rec & 255;
        unsigned short s = (unsigned short)(rec >> 16);
        int p = atomicAdd(&lfill[d8], 1);
        if (lds) img[p] = s;
        else col[rbase + p] = s;
    }
    __syncthreads();
    if (lds) {
        for (int i = t; i < size; i += 256) col[rbase + i] = img[i];
    }
}

// ---------------- GEMM1: X fp32 [n,128] @ W1 [128,128] -> h1h fp16 + alphas ----

__global__ __launch_bounds__(256) void gemm1_mfma_kernel(const float* __restrict__ X,
                                                         const float* __restrict__ W,
                                                         __half* __restrict__ outh,
                                                         const float* __restrict__ a_src,
                                                         const float* __restrict__ a_dst,
                                                         float* __restrict__ as_out,
                                                         float* __restrict__ ad_out, int nrows) {
    constexpr int KP = 136;
    __shared__ _Float16 wlds[128 * KP];  // wlds[n][k] = W[k][n]
    int t = threadIdx.x;
    int wv = t >> 6, lane = t & 63;
    int quad = lane >> 4, m16 = lane & 15;
    for (int i = t; i < 4096; i += 256) {
        int k = i >> 5;
        int n0 = (i & 31) << 2;
        float4 v = *(const float4*)(W + k * 128 + n0);
        wlds[(n0 + 0) * KP + k] = (_Float16)v.x;
        wlds[(n0 + 1) * KP + k] = (_Float16)v.y;
        wlds[(n0 + 2) * KP + k] = (_Float16)v.z;
        wlds[(n0 + 3) * KP + k] = (_Float16)v.w;
    }
    __syncthreads();

    int row = blockIdx.x * 64 + wv * 16 + m16;
    int rowC = min(row, nrows - 1);
    const float* xp = X + (size_t)rowC * 128;

    f32x4 acc[8];
#pragma unroll
    for (int nt = 0; nt < 8; ++nt) acc[nt] = (f32x4)0.f;

    for (int kt = 0; kt < 128; kt += 32) {
        float4 v0 = *(const float4*)(xp + kt + quad * 8);
        float4 v1 = *(const float4*)(xp + kt + quad * 8 + 4);
        f16x8 af;
        af[0] = (_Float16)v0.x; af[1] = (_Float16)v0.y;
        af[2] = (_Float16)v0.z; af[3] = (_Float16)v0.w;
        af[4] = (_Float16)v1.x; af[5] = (_Float16)v1.y;
        af[6] = (_Float16)v1.z; af[7] = (_Float16)v1.w;
#pragma unroll
        for (int nt = 0; nt < 8; ++nt) {
            f16x8 bf = *(const f16x8*)(&wlds[(nt * 16 + m16) * KP + kt + quad * 8]);
            acc[nt] = __builtin_amdgcn_mfma_f32_16x16x32_f16(af, bf, acc[nt], 0, 0, 0);
        }
    }

    float aS[8], aD[8];
#pragma unroll
    for (int nt = 0; nt < 8; ++nt) {
        aS[nt] = a_src[nt * 16 + m16];
        aD[nt] = a_dst[nt * 16 + m16];
    }
    int rowBaseW = blockIdx.x * 64 + wv * 16;
#pragma unroll
    for (int r = 0; r < 4; ++r) {
        int orow = rowBaseW + quad * 4 + r;
        bool ov = orow < nrows;
        if (ov) {
#pragma unroll
            for (int nt = 0; nt < 8; ++nt)
                outh[(size_t)orow * 128 + nt * 16 + m16] = __float2half(acc[nt][r]);
        }
#pragma unroll
        for (int h = 0; h < 4; ++h) {
            float ss = acc[2 * h][r] * aS[2 * h] + acc[2 * h + 1][r] * aS[2 * h + 1];
            float dd = acc[2 * h][r] * aD[2 * h] + acc[2 * h + 1][r] * aD[2 * h + 1];
#pragma unroll
            for (int o = 1; o < 16; o <<= 1) {
                ss += __shfl_xor(ss, o, 64);
                dd += __shfl_xor(dd, o, 64);
            }
            if (ov && m16 == h) {
                as_out[orow * 4 + h] = ss;
                ad_out[orow * 4 + h] = dd;
            }
        }
    }
}

// ---------------- GEMM2: h2in fp16 [n,128] @ W2 [128,64] -> h2bh fp16 + alphas --

__global__ __launch_bounds__(256) void gemm2_mfma_kernel(const __half* __restrict__ Xh,
                                                         const float* __restrict__ W,
                                                         __half* __restrict__ outh,
                                                         const float* __restrict__ a_src,
                                                         const float* __restrict__ a_dst,
                                                         float* __restrict__ as_out,
                                                         float* __restrict__ ad_out, int nrows) {
    constexpr int KP = 136;
    __shared__ _Float16 wlds[64 * KP];
    int t = threadIdx.x;
    int wv = t >> 6, lane = t & 63;
    int quad = lane >> 4, m16 = lane & 15;
    for (int i = t; i < 2048; i += 256) {
        int k = i >> 4;
        int n0 = (i & 15) << 2;
        float4 v = *(const float4*)(W + k * 64 + n0);
        wlds[(n0 + 0) * KP + k] = (_Float16)v.x;
        wlds[(n0 + 1) * KP + k] = (_Float16)v.y;
        wlds[(n0 + 2) * KP + k] = (_Float16)v.z;
        wlds[(n0 + 3) * KP + k] = (_Float16)v.w;
    }
    __syncthreads();

    int row = blockIdx.x * 64 + wv * 16 + m16;
    int rowC = min(row, nrows - 1);
    const _Float16* xp = (const _Float16*)Xh + (size_t)rowC * 128;

    f32x4 acc[4];
#pragma unroll
    for (int nt = 0; nt < 4; ++nt) acc[nt] = (f32x4)0.f;

    for (int kt = 0; kt < 128; kt += 32) {
        f16x8 af = *(const f16x8*)(xp + kt + quad * 8);
#pragma unroll
        for (int nt = 0; nt < 4; ++nt) {
            f16x8 bf = *(const f16x8*)(&wlds[(nt * 16 + m16) * KP + kt + quad * 8]);
            acc[nt] = __builtin_amdgcn_mfma_f32_16x16x32_f16(af, bf, acc[nt], 0, 0, 0);
        }
    }

    float aS[4], aD[4];
#pragma unroll
    for (int nt = 0; nt < 4; ++nt) {
        aS[nt] = a_src[nt * 16 + m16];
        aD[nt] = a_dst[nt * 16 + m16];
    }
    int rowBaseW = blockIdx.x * 64 + wv * 16;
#pragma unroll
    for (int r = 0; r < 4; ++r) {
        int orow = rowBaseW + quad * 4 + r;
        bool ov = orow < nrows;
        if (ov) {
#pragma unroll
            for (int nt = 0; nt < 4; ++nt)
                outh[(size_t)orow * 64 + nt * 16 + m16] = __float2half(acc[nt][r]);
        }
        float ss = 0.f, dd = 0.f;
#pragma unroll
        for (int nt = 0; nt < 4; ++nt) {
            ss = fmaf(acc[nt][r], aS[nt], ss);
            dd = fmaf(acc[nt][r], aD[nt], dd);
        }
#pragma unroll
        for (int o = 1; o < 16; o <<= 1) {
            ss += __shfl_xor(ss, o, 64);
            dd += __shfl_xor(dd, o, 64);
        }
        if (ov && m16 == 0) {
            as_out[orow] = ss;
            ad_out[orow] = dd;
        }
    }
}

// ---------------- aggregation ----------------

// layer 1: one wave per dst node. Lane: group g=lane>>4 (4 edges concurrent),
// channel block c16=lane&15 (8 ch, 16B loads), head=(c16)>>2. Phase-1 p layout
// unchanged: lane (j16*4+h) holds p for edge e*16+j16, head h (0 if padded).
__global__ __launch_bounds__(256) void agg1_kernel(const __half* __restrict__ h1h,
                                                   const float* __restrict__ asrc,
                                                   const float* __restrict__ adst,
                                                   const int* __restrict__ row_ptr,
                                                   const unsigned short* __restrict__ col,
                                                   const float* __restrict__ b1,
                                                   __half* __restrict__ out, int n) {
    int wave = threadIdx.x >> 6;
    int lane = threadIdx.x & 63;
    int node = blockIdx.x * 4 + wave;
    if (node >= n) return;
    int g = lane >> 4;       // edge group
    int c16 = lane & 15;     // channel block (8 ch)
    int headA = c16 >> 2;    // head of these channels
    int hp1 = lane & 3;      // phase-1 head role
    int j16 = lane >> 2;     // phase-1 edge role
    float ad1 = adst[node * 4 + hp1];
    int start = row_ptr[node], end = row_ptr[node + 1];
    float acc[8];
#pragma unroll
    for (int k = 0; k < 8; ++k) acc[k] = 0.f;
    float s = 0.f;
    const _Float16* hp = (const _Float16*)h1h;
    for (int base = start; base < end; base += 64) {
        int idx = base + lane;
        int cnt = min(64, end - base);
        int myS = (idx < end) ? (int)col[idx] : 0;
        // phase 1: p per (edge, head)
        float pr[4];
#pragma unroll
        for (int e = 0; e < 4; ++e) {
            int j = e * 16 + j16;
            int srcj = __shfl(myS, j, 64);
            float ev = asrc[srcj * 4 + hp1] + ad1;
            ev = (ev > 0.f) ? ev : LRELU_SLOPE * ev;
            pr[e] = (j < cnt) ? __expf(ev) : 0.f;
        }
        // phase 2: 4 edges per iteration (one per group), 16B/lane
#pragma unroll
        for (int e = 0; e < 4; ++e) {
            int ebase = e << 4;
            if (ebase < cnt) {
                float pre = pr[e];
                int lim = min(ebase + 16, cnt);
                for (int j0 = ebase; j0 < lim; j0 += 4) {
                    int edge = j0 + g;  // <= 63 always
                    unsigned src = (unsigned)__shfl(myS, edge, 64);
                    float p = __shfl(pre, ((edge & 15) << 2) + headA, 64);
                    f16x8 hv = *(const f16x8*)(hp + ((size_t)src << 7) + (c16 << 3));
#pragma unroll
                    for (int k = 0; k < 8; ++k) acc[k] = fmaf(p, (float)hv[k], acc[k]);
                    s += p;
                }
            }
        }
    }
    // combine the 4 edge groups
    s += __shfl_xor(s, 16, 64);
    s += __shfl_xor(s, 32, 64);
#pragma unroll
    for (int k = 0; k < 8; ++k) {
        acc[k] += __shfl_xor(acc[k], 16, 64);
        acc[k] += __shfl_xor(acc[k], 32, 64);
    }
    if (g == 0) {
        float inv = 1.f / (s + 1e-16f);
        float4 bb0 = ((const float4*)b1)[c16 * 2];
        float4 bb1 = ((const float4*)b1)[c16 * 2 + 1];
        f16x8 o;
        o[0] = (_Float16)fmaxf(acc[0] * inv + bb0.x, 0.f);
        o[1] = (_Float16)fmaxf(acc[1] * inv + bb0.y, 0.f);
        o[2] = (_Float16)fmaxf(acc[2] * inv + bb0.z, 0.f);
        o[3] = (_Float16)fmaxf(acc[3] * inv + bb0.w, 0.f);
        o[4] = (_Float16)fmaxf(acc[4] * inv + bb1.x, 0.f);
        o[5] = (_Float16)fmaxf(acc[5] * inv + bb1.y, 0.f);
        o[6] = (_Float16)fmaxf(acc[6] * inv + bb1.z, 0.f);
        o[7] = (_Float16)fmaxf(acc[7] * inv + bb1.w, 0.f);
        *(f16x8*)((_Float16*)out + ((size_t)node << 7) + (c16 << 3)) = o;
    }
}

// layer 2: one wave per dst node. group g=lane>>3 (8 edges concurrent),
// channel block c8=lane&7 (8 ch, 16B). phase 1: lane j holds p for edge j.
__global__ __launch_bounds__(256) void agg2_kernel(const __half* __restrict__ h2bh,
                                                   const float* __restrict__ asrc,
                                                   const float* __restrict__ adst,
                                                   const int* __restrict__ row_ptr,
                                                   const unsigned short* __restrict__ col,
                                                   const float* __restrict__ b2,
                                                   float* __restrict__ out, int n) {
    int wave = threadIdx.x >> 6;
    int lane = threadIdx.x & 63;
    int node = blockIdx.x * 4 + wave;
    if (node >= n) return;
    int g = lane >> 3;
    int c8 = lane & 7;
    float ad = adst[node];
    int start = row_ptr[node], end = row_ptr[node + 1];
    float acc[8];
#pragma unroll
    for (int k = 0; k < 8; ++k) acc[k] = 0.f;
    float s = 0.f;
    const _Float16* hp = (const _Float16*)h2bh;
    for (int base = start; base < end; base += 64) {
        int idx = base + lane;
        int cnt = min(64, end - base);
        int myS = (idx < end) ? (int)col[idx] : 0;
        float ev = asrc[myS] + ad;
        ev = (ev > 0.f) ? ev : LRELU_SLOPE * ev;
        float pr = (lane < cnt) ? __expf(ev) : 0.f;
        for (int j0 = 0; j0 < cnt; j0 += 8) {
            int edge = j0 + g;  // <= 63 always
            unsigned src = (unsigned)__shfl(myS, edge, 64);
            float p = __shfl(pr, edge, 64);
            f16x8 hv = *(const f16x8*)(hp + ((size_t)src << 6) + (c8 << 3));
#pragma unroll
            for (int k = 0; k < 8; ++k) acc[k] = fmaf(p, (float)hv[k], acc[k]);
            s += p;
        }
    }
    s += __shfl_xor(s, 8, 64);
    s += __shfl_xor(s, 16, 64);
    s += __shfl_xor(s, 32, 64);
#pragma unroll
    for (int k = 0; k < 8; ++k) {
        acc[k] += __shfl_xor(acc[k], 8, 64);
        acc[k] += __shfl_xor(acc[k], 16, 64);
        acc[k] += __shfl_xor(acc[k], 32, 64);
    }
    if (g == 0) {
        float inv = 1.f / (s + 1e-16f);
        float4 bb0 = ((const float4*)b2)[c8 * 2];
        float4 bb1 = ((const float4*)b2)[c8 * 2 + 1];
        float4 o0, o1;
        o0.x = acc[0] * inv + bb0.x;
        o0.y = acc[1] * inv + bb0.y;
        o0.z = acc[2] * inv + bb0.z;
        o0.w = acc[3] * inv + bb0.w;
        o1.x = acc[4] * inv + bb1.x;
        o1.y = acc[5] * inv + bb1.y;
        o1.z = acc[6] * inv + bb1.z;
        o1.w = acc[7] * inv + bb1.w;
        float* op = out + (size_t)node * 64 + c8 * 8;
        *(float4*)op = o0;
        *(float4*)(op + 4) = o1;
    }
}

// ---------------- launch ----------------

extern "C" void kernel_launch(void* const* d_in, const int* in_sizes, int n_in,
                              void* d_out, int out_size, void* d_ws, size_t ws_size,
                              hipStream_t stream) {
    const float* x      = (const float*)d_in[0];
    const int*   ei     = (const int*)d_in[1];
    const float* W1     = (const float*)d_in[2];
    const float* a_src1 = (const float*)d_in[3];
    const float* a_dst1 = (const float*)d_in[4];
    const float* b1     = (const float*)d_in[5];
    const float* W2     = (const float*)d_in[6];
    const float* a_src2 = (const float*)d_in[7];
    const float* a_dst2 = (const float*)d_in[8];
    const float* b2     = (const float*)d_in[9];
    float* out = (float*)d_out;

    const int N = in_sizes[0] / 128;
    const int E = in_sizes[1] / 2;
    const int total = E + N;
    const int nBuckets = (N + 255) >> 8;   // 196

    char* ws = (char*)d_ws;
    size_t off = 0;
    auto alloc = [&](size_t bytes) {
        void* p = ws + off;
        off += (bytes + 255) & ~(size_t)255;
        return p;
    };
    float* regionA = (float*)alloc((size_t)N * 128 * 4);
    __half* h1h   = (__half*)alloc((size_t)N * 128 * 2);
    __half* h2bh  = (__half*)alloc((size_t)N * 64 * 2);
    float* asrc1  = (float*)alloc((size_t)N * 4 * 4);
    float* adst1  = (float*)alloc((size_t)N * 4 * 4);
    float* asrc2  = (float*)alloc((size_t)N * 4);
    float* adst2  = (float*)alloc((size_t)N * 4);
    int*   row_ptr= (int*)alloc((size_t)(N + 1) * 4);
    int*   gfill  = (int*)alloc((size_t)nBuckets * 4);
    int*   bsums  = (int*)alloc((size_t)nBuckets * 4);
    unsigned short* col = (unsigned short*)alloc((size_t)total * 2);

    unsigned int* records = (unsigned int*)regionA;          // 12.8MB
    int* hist = (int*)(regionA + (size_t)NBMAX * BCAP);      // +400KB
    __half* h2in = (__half*)regionA;                         // after CSR build
    (void)ws_size; (void)n_in; (void)out_size;

    const int* ei_src = ei;
    const int* ei_dst = ei + E;

    // CSR build (counting sort by dst bucket)
    const int chunk = (E + NBLK - 1) / NBLK;
    hist_kernel<<<NBLK, 256, 0, stream>>>(ei_dst, hist, E, chunk);
    bucket_scan_kernel<<<nBuckets, NBLK, 0, stream>>>(hist, gfill);
    scatter2_kernel<<<NBLK, 256, 0, stream>>>(ei_src, ei_dst, hist, records, E, chunk);
    scan_blocksums_kernel<<<1, 256, 0, stream>>>(gfill, bsums, row_ptr, nBuckets, N, total);
    csr_build_kernel<<<nBuckets, 256, 0, stream>>>(records, gfill, bsums, row_ptr, col, N);

    // layer 1
    gemm1_mfma_kernel<<<(N + 63) / 64, 256, 0, stream>>>(x, W1, h1h, a_src1, a_dst1,
                                                         asrc1, adst1, N);
    agg1_kernel<<<(N + 3) / 4, 256, 0, stream>>>(h1h, asrc1, adst1,
                                                 row_ptr, col, b1, h2in, N);

    // layer 2
    gemm2_mfma_kernel<<<(N + 63) / 64, 256, 0, stream>>>(h2in, W2, h2bh, a_src2, a_dst2,
                                                         asrc2, adst2, N);
    agg2_kernel<<<(N + 3) / 4, 256, 0, stream>>>(h2bh, asrc2, adst2,
                                                 row_ptr, col, b2, out, N);
}